// Round 15
// baseline (1846.946 us; speedup 1.0000x reference)
//
#include <hip/hip_runtime.h>
#include <math.h>

#define NB 8
#define NN 4096
#define NS 1024
#define NC 128
#define MID 64
#define CIN 131
#define COUT 256
#define PSTRIDE (2048 * 262)
#define SSTRIDE (256 * 512)

typedef float v2f __attribute__((ext_vector_type(2)));

// ---- DPP helpers ----
template <int N>
__device__ __forceinline__ float dpp_ror(float x) {
  return __int_as_float(
      __builtin_amdgcn_update_dpp(0, __float_as_int(x), 0x120 + N, 0xF, 0xF, false));
}
template <int CTRL>
__device__ __forceinline__ float dpp_bc(float x) {
  return __int_as_float(
      __builtin_amdgcn_update_dpp(0, __float_as_int(x), CTRL, 0xF, 0xF, false));
}
__device__ __forceinline__ float rdlane63(float v) {
  return __int_as_float(__builtin_amdgcn_readlane(__float_as_int(v), 63));
}
__device__ __forceinline__ float wave_umax64(float v) {
  v = fmaxf(v, dpp_ror<1>(v)); v = fmaxf(v, dpp_ror<2>(v));
  v = fmaxf(v, dpp_ror<4>(v)); v = fmaxf(v, dpp_ror<8>(v));
  v = fmaxf(v, dpp_bc<0x142>(v));
  v = fmaxf(v, dpp_bc<0x143>(v));
  return rdlane63(v);
}
__device__ __forceinline__ float wave_usum(float v) {
  v += dpp_ror<1>(v); v += dpp_ror<2>(v); v += dpp_ror<4>(v); v += dpp_ror<8>(v);
  v += dpp_bc<0x142>(v);
  v += dpp_bc<0x143>(v);
  return rdlane63(v);
}
__device__ __forceinline__ void wave_usum4(float& a, float& b, float& c, float& d) {
  a += dpp_ror<1>(a); b += dpp_ror<1>(b); c += dpp_ror<1>(c); d += dpp_ror<1>(d);
  a += dpp_ror<2>(a); b += dpp_ror<2>(b); c += dpp_ror<2>(c); d += dpp_ror<2>(d);
  a += dpp_ror<4>(a); b += dpp_ror<4>(b); c += dpp_ror<4>(c); d += dpp_ror<4>(d);
  a += dpp_ror<8>(a); b += dpp_ror<8>(b); c += dpp_ror<8>(c); d += dpp_ror<8>(d);
  a += dpp_bc<0x142>(a); b += dpp_bc<0x142>(b); c += dpp_bc<0x142>(c); d += dpp_bc<0x142>(d);
  a += dpp_bc<0x143>(a); b += dpp_bc<0x143>(b); c += dpp_bc<0x143>(c); d += dpp_bc<0x143>(d);
  a = rdlane63(a); b = rdlane63(b); c = rdlane63(c); d = rdlane63(d);
}
__device__ __forceinline__ void wave_umax4_64(float& a, float& b, float& c, float& d) {
  a = fmaxf(a, dpp_ror<1>(a)); b = fmaxf(b, dpp_ror<1>(b)); c = fmaxf(c, dpp_ror<1>(c)); d = fmaxf(d, dpp_ror<1>(d));
  a = fmaxf(a, dpp_ror<2>(a)); b = fmaxf(b, dpp_ror<2>(b)); c = fmaxf(c, dpp_ror<2>(c)); d = fmaxf(d, dpp_ror<2>(d));
  a = fmaxf(a, dpp_ror<4>(a)); b = fmaxf(b, dpp_ror<4>(b)); c = fmaxf(c, dpp_ror<4>(c)); d = fmaxf(d, dpp_ror<4>(d));
  a = fmaxf(a, dpp_ror<8>(a)); b = fmaxf(b, dpp_ror<8>(b)); c = fmaxf(c, dpp_ror<8>(c)); d = fmaxf(d, dpp_ror<8>(d));
  a = fmaxf(a, dpp_bc<0x142>(a)); b = fmaxf(b, dpp_bc<0x142>(b)); c = fmaxf(c, dpp_bc<0x142>(c)); d = fmaxf(d, dpp_bc<0x142>(d));
  a = fmaxf(a, dpp_bc<0x143>(a)); b = fmaxf(b, dpp_bc<0x143>(b)); c = fmaxf(c, dpp_bc<0x143>(c)); d = fmaxf(d, dpp_bc<0x143>(d));
  a = rdlane63(a); b = rdlane63(b); c = rdlane63(c); d = rdlane63(d);
}
__device__ __forceinline__ float wave_max32(float v) {
  v = fmaxf(v, dpp_ror<1>(v)); v = fmaxf(v, dpp_ror<2>(v));
  v = fmaxf(v, dpp_ror<4>(v)); v = fmaxf(v, dpp_ror<8>(v));
  v = fmaxf(v, __shfl_xor(v, 16));
  return v;
}
__device__ __forceinline__ void wave_max4_32(float& a, float& b, float& c, float& d) {
  a = fmaxf(a, dpp_ror<1>(a)); b = fmaxf(b, dpp_ror<1>(b)); c = fmaxf(c, dpp_ror<1>(c)); d = fmaxf(d, dpp_ror<1>(d));
  a = fmaxf(a, dpp_ror<2>(a)); b = fmaxf(b, dpp_ror<2>(b)); c = fmaxf(c, dpp_ror<2>(c)); d = fmaxf(d, dpp_ror<2>(d));
  a = fmaxf(a, dpp_ror<4>(a)); b = fmaxf(b, dpp_ror<4>(b)); c = fmaxf(c, dpp_ror<4>(c)); d = fmaxf(d, dpp_ror<4>(d));
  a = fmaxf(a, dpp_ror<8>(a)); b = fmaxf(b, dpp_ror<8>(b)); c = fmaxf(c, dpp_ror<8>(c)); d = fmaxf(d, dpp_ror<8>(d));
  a = fmaxf(a, __shfl_xor(a, 16)); b = fmaxf(b, __shfl_xor(b, 16));
  c = fmaxf(c, __shfl_xor(c, 16)); d = fmaxf(d, __shfl_xor(d, 16));
}

// ---------------------------------------------------------------- FPS v8
// 256 threads (r13's proven shape) + fmax-only inner loop + leader
// post-scan: leader finds first q with dd[q]==bv (descending overwrite =
// first index; identical decision to ascending strict->) and writes
// {u64 key, winner xyz FROM REGISTERS} to LDS. All threads 4-way
// key-compare selecting xyz — no dependent pts[li] LDS read.
// Exact-max DPP reduce + min-lane ballot: bit-identical selections.
__global__ __launch_bounds__(256) void fps_kernel(const float* __restrict__ xyz,
                                                  float* __restrict__ out) {
#pragma clang fp contract(off)
  const int b = blockIdx.x;
  const int tid = threadIdx.x;
  const int lane = tid & 63, w = tid >> 6;
  __shared__ float4 pts[NN];
  __shared__ int sel[NS];
  __shared__ unsigned long long wkey[2][4];
  __shared__ float4 wxyz[2][4];
  const float* base = xyz + (size_t)b * NN * 3;
  for (int t = tid; t < NN; t += 256)
    pts[t] = make_float4(base[3 * t], base[3 * t + 1], base[3 * t + 2], 0.f);
  if (tid == 0) sel[0] = 0;
  __syncthreads();
  float px[16], py[16], pz[16], dd[16];
#pragma unroll
  for (int q = 0; q < 16; q++) {
    float4 P = pts[tid * 16 + q];
    px[q] = P.x; py[q] = P.y; pz[q] = P.z; dd[q] = 1e10f;
  }
  float lx = pts[0].x, ly = pts[0].y, lz = pts[0].z;
  for (int it = 1; it < NS; ++it) {
    float bv = -1.0f;
#pragma unroll
    for (int q = 0; q < 16; q++) {
      float dx = px[q] - lx, dy = py[q] - ly, dz = pz[q] - lz;
      float d2 = dx * dx + dy * dy + dz * dz;
      float dn = fminf(dd[q], d2);
      dd[q] = dn;
      bv = fmaxf(bv, dn);                    // value only — no index tracking
    }
    float swm = wave_umax64(bv);
    unsigned long long msk = __ballot(bv == swm);
    int srcl = __ffsll(msk) - 1;             // min lane = min j (contiguous chunks)
    const int p = it & 1;
    if (lane == srcl) {
      int bq = 0;
#pragma unroll
      for (int q = 15; q >= 0; --q)
        if (dd[q] == bv) bq = q;             // descending overwrite -> first q
      wkey[p][w] =
          ((unsigned long long)__float_as_uint(swm) << 32) | (unsigned)(65535 - (tid * 16 + bq));
      wxyz[p][w] = make_float4(px[bq], py[bq], pz[bq], 0.f);
    }
    __syncthreads();
    unsigned long long k0 = wkey[p][0], k1 = wkey[p][1], k2 = wkey[p][2], k3 = wkey[p][3];
    float4 x0 = wxyz[p][0], x1 = wxyz[p][1], x2 = wxyz[p][2], x3 = wxyz[p][3];
    unsigned long long ka = k0; float4 xa = x0;
    if (k1 > ka) { ka = k1; xa = x1; }
    unsigned long long kb = k2; float4 xb = x2;
    if (k3 > kb) { kb = k3; xb = x3; }
    unsigned long long kk = ka; float4 xw = xa;
    if (kb > kk) { kk = kb; xw = xb; }
    if (tid == 0) sel[it] = 65535 - (int)(kk & 0xFFFFu);
    lx = xw.x; ly = xw.y; lz = xw.z;
  }
  __syncthreads();
  for (int s = tid; s < NS; s += 256) {
    float4 P = pts[sel[s]];
    float* o = out + ((size_t)b * NS + s) * 3;
    o[0] = P.x; o[1] = P.y; o[2] = P.z;
  }
}

// ---------------------------------------------------------------- features (B,C,N)->(B,N,C)
__global__ void ft_kernel(const float* __restrict__ f, float* __restrict__ ft) {
  __shared__ float tile[32][33];
  int n0 = blockIdx.x * 32, c0 = blockIdx.y * 32, b = blockIdx.z;
  int tx = threadIdx.x, ty = threadIdx.y;  // 32x8
  for (int r = 0; r < 32; r += 8)
    tile[ty + r][tx] = f[((size_t)b * NC + (c0 + ty + r)) * NN + n0 + tx];
  __syncthreads();
  for (int r = 0; r < 32; r += 8)
    ft[((size_t)b * NN + n0 + ty + r) * NC + c0 + tx] = tile[tx][ty + r];
}

// ---------------------------------------------------------------- Wcr (256,131) -> (131,256)
__global__ void wcrt_kernel(const float* __restrict__ Wcr, float* __restrict__ wcrT) {
  int t = blockIdx.x * blockDim.x + threadIdx.x;
  if (t >= CIN * COUT) return;
  int c = t % COUT, d = t / COUT;
  wcrT[t] = Wcr[c * CIN + d];
}

// ---------------------------------------------------------------- ball query v2 (both scales)
__global__ __launch_bounds__(256) void ball_kernel(const float* __restrict__ xyz,
                                                   const float* __restrict__ nxyz,
                                                   int* __restrict__ idx0,
                                                   int* __restrict__ idx1) {
#pragma clang fp contract(off)
  __shared__ float4 pts[NN];
  const int scale = blockIdx.y;
  const int K = scale ? 64 : 32;
  const float r2 = scale ? 0.04f : 0.01f;
  int* __restrict__ idx = scale ? idx1 : idx0;
  const int lane = threadIdx.x & 63, w = threadIdx.x >> 6;
  const int c0 = blockIdx.x * 64;
  const int b = c0 >> 10;
  const float* base = xyz + (size_t)b * NN * 3;
  for (int t = threadIdx.x; t < NN; t += 256)
    pts[t] = make_float4(base[3 * t], base[3 * t + 1], base[3 * t + 2], 0.f);
  __syncthreads();
  const unsigned long long ltmask = (1ull << lane) - 1;
  for (int ci = 0; ci < 16; ci++) {
    const int center = c0 + w * 16 + ci;
    const float cx = nxyz[center * 3], cy = nxyz[center * 3 + 1], cz = nxyz[center * 3 + 2];
    int cnt = 0, first = -1;
    int* o = idx + (size_t)center * K;
    for (int st64 = 0; st64 < 64; st64++) {
      const int j = st64 * 64 + lane;
      float4 P = pts[j];
      float dx = P.x - cx, dy = P.y - cy, dz = P.z - cz;
      float d2 = dx * dx + dy * dy + dz * dz;
      const bool hit = d2 < r2;
      unsigned long long mask = __ballot(hit);
      int pos = cnt + __popcll(mask & ltmask);
      if (hit && pos < K) o[pos] = j;
      if (first < 0 && mask) first = st64 * 64 + __ffsll(mask) - 1;
      cnt += __popcll(mask);
      if (cnt >= K) break;
    }
    if (cnt < K && lane >= cnt && lane < K) o[lane] = first;
  }
}

// ---------------------------------------------------------------- P1 (both scales, 4-ch batch)
__global__ __launch_bounds__(256) void p1_kernel(
    const float* __restrict__ xyz, const float* __restrict__ nxyz,
    const int* __restrict__ idx0, const int* __restrict__ idx1,
    const float* __restrict__ W1, const float* __restrict__ b1,
    float* __restrict__ parts) {
  __shared__ float accS[MID], accQ[MID];
  const int scale = blockIdx.y;
  const int nblk = scale ? 2048 : 1024;
  if ((int)blockIdx.x >= nblk) return;
  const int K = scale ? 64 : 32, ksh = scale ? 6 : 5, G = scale ? 1 : 2;
  const int* __restrict__ idx = scale ? idx1 : idx0;
  float* __restrict__ partials = parts + (size_t)scale * PSTRIDE + (size_t)blockIdx.x * (2 * MID);
  const int tid = threadIdx.x, lane = tid & 63, wave = tid >> 6;
  if (tid < MID) { accS[tid] = 0.f; accQ[tid] = 0.f; }
  __syncthreads();
  const int sub = lane >> ksh;
  const int k = lane & (K - 1);
  const int center = blockIdx.x * (4 * G) + wave * G + sub;
  const int b = center >> 10;
  const int* ip = idx + (size_t)center * K;
  const int j = ip[k];
  const int j0 = ip[0];
  const float* xb = xyz + (size_t)b * NN * 3;
  const float gxx = xb[3 * j], gxy = xb[3 * j + 1], gxz = xb[3 * j + 2];
  const float c0x = xb[3 * j0], c0y = xb[3 * j0 + 1], c0z = xb[3 * j0 + 2];
  const float cx = nxyz[center * 3], cy = nxyz[center * 3 + 1], cz = nxyz[center * 3 + 2];
  const float rx = gxx - cx, ry = gxy - cy, rz = gxz - cz;
  const float dst = sqrtf(rx * rx + ry * ry + rz * rz + 1e-12f);
  float h[10] = {dst, c0x, c0y, c0z, gxx, gxy, gxz, rx, ry, rz};
#pragma unroll
  for (int c = 0; c < MID; c += 4) {
    float a0 = b1[c], a1 = b1[c + 1], a2 = b1[c + 2], a3 = b1[c + 3];
    const float* w0 = W1 + c * 10;
    const float* w1 = w0 + 10;
    const float* w2 = w0 + 20;
    const float* w3 = w0 + 30;
#pragma unroll
    for (int d = 0; d < 10; d++) {
      a0 += h[d] * w0[d]; a1 += h[d] * w1[d]; a2 += h[d] * w2[d]; a3 += h[d] * w3[d];
    }
    float v0 = a0, v1 = a1, v2 = a2, v3 = a3;
    wave_usum4(v0, v1, v2, v3);
    float q0 = a0 * a0, q1 = a1 * a1, q2 = a2 * a2, q3 = a3 * a3;
    wave_usum4(q0, q1, q2, q3);
    if (lane == 0) {
      atomicAdd(&accS[c], v0); atomicAdd(&accS[c + 1], v1);
      atomicAdd(&accS[c + 2], v2); atomicAdd(&accS[c + 3], v3);
      atomicAdd(&accQ[c], q0); atomicAdd(&accQ[c + 1], q1);
      atomicAdd(&accQ[c + 2], q2); atomicAdd(&accQ[c + 3], q3);
    }
  }
  __syncthreads();
  for (int t = tid; t < 2 * MID; t += 256)
    partials[t] = (t < MID ? accS[t] : accQ[t - MID]);
}

// ---------------------------------------------------------------- column reduce (both scales)
__global__ __launch_bounds__(256) void red2_kernel(const float* __restrict__ pbase,
                                                   int pstride, int nb0, int nb1,
                                                   double* __restrict__ stats, int obase) {
  __shared__ double red[256];
  const int scale = blockIdx.y;
  const int nblk = scale ? nb1 : nb0;
  const float* part = pbase + (size_t)scale * pstride;
  double* st = stats + scale * 1024;
  const int c = blockIdx.x;
  const int ncol = gridDim.x;
  double a = 0.0;
  for (int r = threadIdx.x; r < nblk; r += 256)
    a += (double)part[(size_t)r * ncol + c];
  red[threadIdx.x] = a;
  __syncthreads();
  for (int s = 128; s > 0; s >>= 1) {
    if (threadIdx.x < s) red[threadIdx.x] += red[threadIdx.x + s];
    __syncthreads();
  }
  if (threadIdx.x == 0) st[obase + c] = red[0];
}

// ---------------------------------------------------------------- P2 (both scales)
template <bool UFT>
__global__ __launch_bounds__(256) void p2_kernel(
    const float* __restrict__ xyz, const float* __restrict__ nxyz,
    const float* __restrict__ feat, const float* __restrict__ ft,
    const int* __restrict__ idx0, const int* __restrict__ idx1,
    const float* __restrict__ W1, const float* __restrict__ b1,
    const float* __restrict__ W2, const float* __restrict__ b2,
    const float* __restrict__ g_map, const float* __restrict__ b_map,
    const double* __restrict__ stats, float* __restrict__ pm0,
    float* __restrict__ pm1, float* __restrict__ parts) {
  __shared__ float accS[CIN], accQ[CIN];
  __shared__ float sc1[MID], sh1[MID];
  const int scale = blockIdx.y;
  const int nblk = scale ? 2048 : 1024;
  if ((int)blockIdx.x >= nblk) return;
  const int K = scale ? 64 : 32, ksh = scale ? 6 : 5, G = scale ? 1 : 2;
  const int* __restrict__ idx = scale ? idx1 : idx0;
  float* __restrict__ pm = scale ? pm1 : pm0;
  const double* st = stats + scale * 1024;
  const float* g1 = g_map + scale * MID;
  const float* bt1 = b_map + scale * MID;
  float* __restrict__ partials = parts + (size_t)scale * PSTRIDE + (size_t)blockIdx.x * (2 * CIN);
  const int tid = threadIdx.x, lane = tid & 63, wave = tid >> 6;
  for (int t = tid; t < CIN; t += 256) { accS[t] = 0.f; accQ[t] = 0.f; }
  if (tid < MID) {
    const double cnt = (double)NB * NS * K;
    double mean = st[tid] / cnt;
    double var = st[64 + tid] / cnt - mean * mean;
    if (var < 0.0) var = 0.0;
    float is = (float)(1.0 / sqrt(var + 1e-5));
    float sc = g1[tid] * is;
    sc1[tid] = sc;
    sh1[tid] = bt1[tid] - (float)mean * sc;
  }
  __syncthreads();
  const int per = nblk >> 3;  // XCD swizzle
  const int lb = ((int)blockIdx.x & 7) * per + ((int)blockIdx.x >> 3);
  const int sub = lane >> ksh;
  const int k = lane & (K - 1);
  const int center = lb * (4 * G) + wave * G + sub;
  const int b = center >> 10;
  const int* ip = idx + (size_t)center * K;
  const int j = ip[k];
  const int j0 = ip[0];
  const float* xb = xyz + (size_t)b * NN * 3;
  const float gxx = xb[3 * j], gxy = xb[3 * j + 1], gxz = xb[3 * j + 2];
  const float c0x = xb[3 * j0], c0y = xb[3 * j0 + 1], c0z = xb[3 * j0 + 2];
  const float cx = nxyz[center * 3], cy = nxyz[center * 3 + 1], cz = nxyz[center * 3 + 2];
  const float rx = gxx - cx, ry = gxy - cy, rz = gxz - cz;
  const float dst = sqrtf(rx * rx + ry * ry + rz * rz + 1e-12f);
  float h[10] = {dst, c0x, c0y, c0z, gxx, gxy, gxz, rx, ry, rz};
  v2f t2[MID / 2];
#pragma unroll
  for (int c = 0; c < MID; c += 2) {
    v2f a = {b1[c], b1[c + 1]};
    const float* w0 = W1 + c * 10;
    const float* w1 = w0 + 10;
#pragma unroll
    for (int d = 0; d < 10; d++) {
      v2f wv = {w0[d], w1[d]};
      v2f hv = {h[d], h[d]};
      a = hv * wv + a;
    }
    v2f sv = {sc1[c], sc1[c + 1]};
    v2f bv = {sh1[c], sh1[c + 1]};
    v2f r = sv * a + bv;
    r[0] = fmaxf(r[0], 0.f); r[1] = fmaxf(r[1], 0.f);
    t2[c >> 1] = r;
  }
  auto chan = [&](int c, float x) {
    const float4* w4 = reinterpret_cast<const float4*>(W2 + (size_t)c * MID);
    v2f zv = {0.f, 0.f};
#pragma unroll
    for (int d4 = 0; d4 < 16; d4++) {
      float4 wq = w4[d4];
      v2f wlo = {wq.x, wq.y}, whi = {wq.z, wq.w};
      zv = t2[2 * d4] * wlo + zv;
      zv = t2[2 * d4 + 1] * whi + zv;
    }
    float z = b2[c] + zv[0] + zv[1];
    float p = z * x;
    float v = wave_usum(p);
    float q = wave_usum(p * p);
    if (lane == 0) { atomicAdd(&accS[c], v); atomicAdd(&accQ[c], q); }
    float pmax = (K == 64) ? wave_umax64(p) : wave_max32(p);
    if (k == (c & (K - 1))) pm[(size_t)center * CIN + c] = pmax;
  };
  auto chan4 = [&](int c, float x0, float x1, float x2, float x3) {
    const float4* wa = reinterpret_cast<const float4*>(W2 + (size_t)(c + 0) * MID);
    const float4* wb = reinterpret_cast<const float4*>(W2 + (size_t)(c + 1) * MID);
    const float4* wc = reinterpret_cast<const float4*>(W2 + (size_t)(c + 2) * MID);
    const float4* wd = reinterpret_cast<const float4*>(W2 + (size_t)(c + 3) * MID);
    v2f z0v = {0.f, 0.f}, z1v = {0.f, 0.f}, z2v = {0.f, 0.f}, z3v = {0.f, 0.f};
#pragma unroll
    for (int d4 = 0; d4 < 16; d4++) {
      v2f tlo = t2[2 * d4], thi = t2[2 * d4 + 1];
      float4 wq;
      wq = wa[d4]; { v2f lo = {wq.x, wq.y}, hi = {wq.z, wq.w}; z0v = tlo * lo + z0v; z0v = thi * hi + z0v; }
      wq = wb[d4]; { v2f lo = {wq.x, wq.y}, hi = {wq.z, wq.w}; z1v = tlo * lo + z1v; z1v = thi * hi + z1v; }
      wq = wc[d4]; { v2f lo = {wq.x, wq.y}, hi = {wq.z, wq.w}; z2v = tlo * lo + z2v; z2v = thi * hi + z2v; }
      wq = wd[d4]; { v2f lo = {wq.x, wq.y}, hi = {wq.z, wq.w}; z3v = tlo * lo + z3v; z3v = thi * hi + z3v; }
    }
    float p0 = (b2[c + 0] + z0v[0] + z0v[1]) * x0;
    float p1 = (b2[c + 1] + z1v[0] + z1v[1]) * x1;
    float p2 = (b2[c + 2] + z2v[0] + z2v[1]) * x2;
    float p3 = (b2[c + 3] + z3v[0] + z3v[1]) * x3;
    float v0 = p0, v1 = p1, v2 = p2, v3 = p3;
    wave_usum4(v0, v1, v2, v3);
    float q0 = p0 * p0, q1 = p1 * p1, q2 = p2 * p2, q3 = p3 * p3;
    wave_usum4(q0, q1, q2, q3);
    if (lane == 0) {
      atomicAdd(&accS[c], v0); atomicAdd(&accS[c + 1], v1);
      atomicAdd(&accS[c + 2], v2); atomicAdd(&accS[c + 3], v3);
      atomicAdd(&accQ[c], q0); atomicAdd(&accQ[c + 1], q1);
      atomicAdd(&accQ[c + 2], q2); atomicAdd(&accQ[c + 3], q3);
    }
    float m0 = p0, m1 = p1, m2 = p2, m3 = p3;
    if (K == 64) wave_umax4_64(m0, m1, m2, m3);
    else wave_max4_32(m0, m1, m2, m3);
    if (k == ((c + 0) & (K - 1))) pm[(size_t)center * CIN + c + 0] = m0;
    if (k == ((c + 1) & (K - 1))) pm[(size_t)center * CIN + c + 1] = m1;
    if (k == ((c + 2) & (K - 1))) pm[(size_t)center * CIN + c + 2] = m2;
    if (k == ((c + 3) & (K - 1))) pm[(size_t)center * CIN + c + 3] = m3;
  };
  chan(0, rx); chan(1, ry); chan(2, rz);
  const float4* ftb4 = UFT ? reinterpret_cast<const float4*>(ft + ((size_t)b * NN + j) * NC)
                           : nullptr;
  const float* fb = feat + (size_t)b * NC * NN + j;
  for (int f0 = 0; f0 < NC; f0 += 4) {
    float4 fr;
    if (UFT) {
      fr = ftb4[f0 >> 2];
    } else {
      fr.x = fb[(size_t)f0 * NN]; fr.y = fb[(size_t)(f0 + 1) * NN];
      fr.z = fb[(size_t)(f0 + 2) * NN]; fr.w = fb[(size_t)(f0 + 3) * NN];
    }
    chan4(3 + f0, fr.x, fr.y, fr.z, fr.w);
  }
  __syncthreads();
  for (int t = tid; t < 2 * CIN; t += 256)
    partials[t] = (t < CIN ? accS[t] : accQ[t - CIN]);
}

// ---------------------------------------------------------------- 131->256 linear (both scales)
__global__ __launch_bounds__(256) void s4_kernel(const float* __restrict__ pm0,
                                                 const float* __restrict__ pm1,
                                                 const float* __restrict__ wcrT,
                                                 const float* __restrict__ bcr,
                                                 const float* __restrict__ g_rs,
                                                 const float* __restrict__ b_rs,
                                                 float* __restrict__ feats,
                                                 const double* __restrict__ stats,
                                                 float* __restrict__ spart) {
  __shared__ float xms[16][132];
  __shared__ float sc2[CIN], sh2[CIN];
  const int scale = blockIdx.y;
  const int K = scale ? 64 : 32;
  const float* pm = scale ? pm1 : pm0;
  const double* st = stats + scale * 1024;
  const float* g2 = g_rs + scale * CIN;
  const float* bt2 = b_rs + scale * CIN;
  const int choff = scale << 8;
  float* sp = spart + (size_t)scale * SSTRIDE + (size_t)blockIdx.x * 512;
  const int tid = threadIdx.x;
  if (tid < CIN) {
    const double cnt = (double)NB * NS * K;
    double mean = st[128 + tid] / cnt;
    double var = st[259 + tid] / cnt - mean * mean;
    if (var < 0.0) var = 0.0;
    float is = (float)(1.0 / sqrt(var + 1e-5));
    float sc = g2[tid] * is;
    sc2[tid] = sc;
    sh2[tid] = bt2[tid] - (float)mean * sc;
  }
  float bc = bcr[tid];
  float s1 = 0.f, s2 = 0.f;
  __syncthreads();
  for (int r0 = blockIdx.x * 16; r0 < NB * NS; r0 += gridDim.x * 16) {
    for (int t = tid; t < 16 * CIN; t += 256) {
      int rr = t / CIN, cc = t % CIN;
      xms[rr][cc] = fmaxf(sc2[cc] * pm[(size_t)(r0 + rr) * CIN + cc] + sh2[cc], 0.0f);
    }
    __syncthreads();
    float acc[16];
#pragma unroll
    for (int u = 0; u < 16; u++) acc[u] = bc;
    for (int d4 = 0; d4 < 32; d4++) {
      float w0 = wcrT[(4 * d4 + 0) * COUT + tid];
      float w1 = wcrT[(4 * d4 + 1) * COUT + tid];
      float w2 = wcrT[(4 * d4 + 2) * COUT + tid];
      float w3 = wcrT[(4 * d4 + 3) * COUT + tid];
#pragma unroll
      for (int u = 0; u < 16; u++) {
        float4 xv = *reinterpret_cast<const float4*>(&xms[u][4 * d4]);
        acc[u] += xv.x * w0 + xv.y * w1 + xv.z * w2 + xv.w * w3;
      }
    }
#pragma unroll
    for (int d = 128; d < CIN; d++) {
      float w = wcrT[d * COUT + tid];
#pragma unroll
      for (int u = 0; u < 16; u++) acc[u] += xms[u][d] * w;
    }
#pragma unroll
    for (int u = 0; u < 16; u++) {
      int r = r0 + u;
      int b = r >> 10, s = r & (NS - 1);
      feats[((size_t)b * 512 + choff + tid) * NS + s] = acc[u];
      s1 += acc[u];
      s2 += acc[u] * acc[u];
    }
    __syncthreads();
  }
  sp[tid] = s1;
  sp[256 + tid] = s2;
}

// ---------------------------------------------------------------- BN3 + relu in place
__global__ void s5_kernel(float* __restrict__ feats, const double* __restrict__ stats,
                          const float* __restrict__ g_cr, const float* __restrict__ b_cr) {
  const int scale = blockIdx.y;
  const double* st = stats + scale * 1024;
  int t = blockIdx.x * blockDim.x + threadIdx.x;
  int s = t & (NS - 1);
  int c = (t >> 10) & (COUT - 1);
  int b = t >> 18;
  double mean = st[512 + c] / (double)(NB * NS);
  double var = st[768 + c] / (double)(NB * NS) - mean * mean;
  if (var < 0.0) var = 0.0;
  float is = (float)(1.0 / sqrt(var + 1e-5));
  float sc = g_cr[scale * 256 + c] * is;
  float sh = b_cr[scale * 256 + c] - (float)mean * sc;
  size_t o = ((size_t)b * 512 + scale * 256 + c) * NS + s;
  feats[o] = fmaxf(sc * feats[o] + sh, 0.0f);
}

// ================================================================ host
extern "C" void kernel_launch(void* const* d_in, const int* in_sizes, int n_in,
                              void* d_out, int out_size, void* d_ws, size_t ws_size,
                              hipStream_t stream) {
  const float* xyz  = (const float*)d_in[0];
  const float* feat = (const float*)d_in[1];
  const float* W1   = (const float*)d_in[2];
  const float* b1   = (const float*)d_in[3];
  const float* W2   = (const float*)d_in[4];
  const float* b2   = (const float*)d_in[5];
  const float* Wcr  = (const float*)d_in[6];
  const float* bcr  = (const float*)d_in[7];
  const float* g_map = (const float*)d_in[8];
  const float* b_map = (const float*)d_in[9];
  const float* g_rs  = (const float*)d_in[10];
  const float* b_rs  = (const float*)d_in[11];
  const float* g_cr  = (const float*)d_in[12];
  const float* b_cr  = (const float*)d_in[13];

  char* wsb = (char*)d_ws;
  size_t off = 0;
  auto take = [&](size_t bytes) -> void* {
    void* p = wsb + off;
    off = (off + bytes + 255) & ~(size_t)255;
    return p;
  };
  int*    idxb0 = (int*)take((size_t)NB * NS * 32 * sizeof(int));
  int*    idxb1 = (int*)take((size_t)NB * NS * 64 * sizeof(int));
  float*  pm0   = (float*)take((size_t)NB * NS * CIN * sizeof(float));
  float*  pm1   = (float*)take((size_t)NB * NS * CIN * sizeof(float));
  float*  wcrT  = (float*)take((size_t)CIN * COUT * sizeof(float));
  double* stats = (double*)take(2048 * sizeof(double));
  float*  parts = (float*)take((size_t)2 * PSTRIDE * sizeof(float));
  float*  spart = (float*)take((size_t)2 * SSTRIDE * sizeof(float));
  float*  ft    = nullptr;
  if (off + (size_t)NB * NN * NC * sizeof(float) + 256 <= ws_size)
    ft = (float*)take((size_t)NB * NN * NC * sizeof(float));

  float* out = (float*)d_out;
  float* feats = out + NB * NS * 3;

  fps_kernel<<<NB, 256, 0, stream>>>(xyz, out);
  if (ft) ft_kernel<<<dim3(NN / 32, NC / 32, NB), dim3(32, 8), 0, stream>>>(feat, ft);
  wcrt_kernel<<<(CIN * COUT + 255) / 256, 256, 0, stream>>>(Wcr, wcrT);
  ball_kernel<<<dim3(128, 2), 256, 0, stream>>>(xyz, out, idxb0, idxb1);
  p1_kernel<<<dim3(2048, 2), 256, 0, stream>>>(xyz, out, idxb0, idxb1, W1, b1, parts);
  red2_kernel<<<dim3(2 * MID, 2), 256, 0, stream>>>(parts, PSTRIDE, 1024, 2048, stats, 0);
  if (ft)
    p2_kernel<true><<<dim3(2048, 2), 256, 0, stream>>>(xyz, out, feat, ft, idxb0, idxb1,
                                                       W1, b1, W2, b2, g_map, b_map,
                                                       stats, pm0, pm1, parts);
  else
    p2_kernel<false><<<dim3(2048, 2), 256, 0, stream>>>(xyz, out, feat, ft, idxb0, idxb1,
                                                        W1, b1, W2, b2, g_map, b_map,
                                                        stats, pm0, pm1, parts);
  red2_kernel<<<dim3(2 * CIN, 2), 256, 0, stream>>>(parts, PSTRIDE, 1024, 2048, stats, 128);
  s4_kernel<<<dim3(256, 2), 256, 0, stream>>>(pm0, pm1, wcrT, bcr, g_rs, b_rs, feats,
                                              stats, spart);
  red2_kernel<<<dim3(512, 2), 256, 0, stream>>>(spart, SSTRIDE, 256, 256, stats, 512);
  s5_kernel<<<dim3((NB * COUT * NS) / 256, 2), 256, 0, stream>>>(feats, stats, g_cr, b_cr);
  (void)in_sizes; (void)n_in; (void)out_size;
}

// Round 16
// 1147.139 us; speedup vs baseline: 1.6100x; 1.6100x over previous
//
#include <hip/hip_runtime.h>
#include <math.h>

#define NB 8
#define NN 4096
#define NS 1024
#define NC 128
#define MID 64
#define CIN 131
#define COUT 256
#define PSTRIDE (2048 * 262)
#define SSTRIDE (256 * 512)

typedef float v2f __attribute__((ext_vector_type(2)));

// ---- DPP helpers ----
template <int N>
__device__ __forceinline__ float dpp_ror(float x) {
  return __int_as_float(
      __builtin_amdgcn_update_dpp(0, __float_as_int(x), 0x120 + N, 0xF, 0xF, false));
}
template <int CTRL>
__device__ __forceinline__ float dpp_bc(float x) {
  return __int_as_float(
      __builtin_amdgcn_update_dpp(0, __float_as_int(x), CTRL, 0xF, 0xF, false));
}
__device__ __forceinline__ float rdlane63(float v) {
  return __int_as_float(__builtin_amdgcn_readlane(__float_as_int(v), 63));
}
__device__ __forceinline__ float wave_umax64(float v) {
  v = fmaxf(v, dpp_ror<1>(v)); v = fmaxf(v, dpp_ror<2>(v));
  v = fmaxf(v, dpp_ror<4>(v)); v = fmaxf(v, dpp_ror<8>(v));
  v = fmaxf(v, dpp_bc<0x142>(v));
  v = fmaxf(v, dpp_bc<0x143>(v));
  return rdlane63(v);
}
__device__ __forceinline__ float wave_usum(float v) {
  v += dpp_ror<1>(v); v += dpp_ror<2>(v); v += dpp_ror<4>(v); v += dpp_ror<8>(v);
  v += dpp_bc<0x142>(v);
  v += dpp_bc<0x143>(v);
  return rdlane63(v);
}
__device__ __forceinline__ void wave_usum4(float& a, float& b, float& c, float& d) {
  a += dpp_ror<1>(a); b += dpp_ror<1>(b); c += dpp_ror<1>(c); d += dpp_ror<1>(d);
  a += dpp_ror<2>(a); b += dpp_ror<2>(b); c += dpp_ror<2>(c); d += dpp_ror<2>(d);
  a += dpp_ror<4>(a); b += dpp_ror<4>(b); c += dpp_ror<4>(c); d += dpp_ror<4>(d);
  a += dpp_ror<8>(a); b += dpp_ror<8>(b); c += dpp_ror<8>(c); d += dpp_ror<8>(d);
  a += dpp_bc<0x142>(a); b += dpp_bc<0x142>(b); c += dpp_bc<0x142>(c); d += dpp_bc<0x142>(d);
  a += dpp_bc<0x143>(a); b += dpp_bc<0x143>(b); c += dpp_bc<0x143>(c); d += dpp_bc<0x143>(d);
  a = rdlane63(a); b = rdlane63(b); c = rdlane63(c); d = rdlane63(d);
}
__device__ __forceinline__ void wave_umax4_64(float& a, float& b, float& c, float& d) {
  a = fmaxf(a, dpp_ror<1>(a)); b = fmaxf(b, dpp_ror<1>(b)); c = fmaxf(c, dpp_ror<1>(c)); d = fmaxf(d, dpp_ror<1>(d));
  a = fmaxf(a, dpp_ror<2>(a)); b = fmaxf(b, dpp_ror<2>(b)); c = fmaxf(c, dpp_ror<2>(c)); d = fmaxf(d, dpp_ror<2>(d));
  a = fmaxf(a, dpp_ror<4>(a)); b = fmaxf(b, dpp_ror<4>(b)); c = fmaxf(c, dpp_ror<4>(c)); d = fmaxf(d, dpp_ror<4>(d));
  a = fmaxf(a, dpp_ror<8>(a)); b = fmaxf(b, dpp_ror<8>(b)); c = fmaxf(c, dpp_ror<8>(c)); d = fmaxf(d, dpp_ror<8>(d));
  a = fmaxf(a, dpp_bc<0x142>(a)); b = fmaxf(b, dpp_bc<0x142>(b)); c = fmaxf(c, dpp_bc<0x142>(c)); d = fmaxf(d, dpp_bc<0x142>(d));
  a = fmaxf(a, dpp_bc<0x143>(a)); b = fmaxf(b, dpp_bc<0x143>(b)); c = fmaxf(c, dpp_bc<0x143>(c)); d = fmaxf(d, dpp_bc<0x143>(d));
  a = rdlane63(a); b = rdlane63(b); c = rdlane63(c); d = rdlane63(d);
}
__device__ __forceinline__ float wave_max32(float v) {
  v = fmaxf(v, dpp_ror<1>(v)); v = fmaxf(v, dpp_ror<2>(v));
  v = fmaxf(v, dpp_ror<4>(v)); v = fmaxf(v, dpp_ror<8>(v));
  v = fmaxf(v, __shfl_xor(v, 16));
  return v;
}
__device__ __forceinline__ void wave_max4_32(float& a, float& b, float& c, float& d) {
  a = fmaxf(a, dpp_ror<1>(a)); b = fmaxf(b, dpp_ror<1>(b)); c = fmaxf(c, dpp_ror<1>(c)); d = fmaxf(d, dpp_ror<1>(d));
  a = fmaxf(a, dpp_ror<2>(a)); b = fmaxf(b, dpp_ror<2>(b)); c = fmaxf(c, dpp_ror<2>(c)); d = fmaxf(d, dpp_ror<2>(d));
  a = fmaxf(a, dpp_ror<4>(a)); b = fmaxf(b, dpp_ror<4>(b)); c = fmaxf(c, dpp_ror<4>(c)); d = fmaxf(d, dpp_ror<4>(d));
  a = fmaxf(a, dpp_ror<8>(a)); b = fmaxf(b, dpp_ror<8>(b)); c = fmaxf(c, dpp_ror<8>(c)); d = fmaxf(d, dpp_ror<8>(d));
  a = fmaxf(a, __shfl_xor(a, 16)); b = fmaxf(b, __shfl_xor(b, 16));
  c = fmaxf(c, __shfl_xor(c, 16)); d = fmaxf(d, __shfl_xor(d, 16));
}

// ---------------------------------------------------------------- FPS v6 (measured best: 601us)
// 256 threads, lane-contiguous chunks (j = tid*16 + q). Per iter: per-lane
// argmax (strict >, ascending q => first-index), all-DPP max reduce,
// ballot(bv==swm)+ffs -> min-lane leader writes u64 key, one barrier,
// 4-key combine, broadcast pts[li] read. contract(off): exact reference
// index decisions.
__global__ __launch_bounds__(256) void fps_kernel(const float* __restrict__ xyz,
                                                  float* __restrict__ out) {
#pragma clang fp contract(off)
  const int b = blockIdx.x;
  const int tid = threadIdx.x;
  const int lane = tid & 63, w = tid >> 6;
  __shared__ float4 pts[NN];
  __shared__ int sel[NS];
  __shared__ unsigned long long wkey[2][4];
  const float* base = xyz + (size_t)b * NN * 3;
  for (int t = tid; t < NN; t += 256)
    pts[t] = make_float4(base[3 * t], base[3 * t + 1], base[3 * t + 2], 0.f);
  if (tid == 0) sel[0] = 0;
  __syncthreads();
  float px[16], py[16], pz[16], dd[16];
#pragma unroll
  for (int q = 0; q < 16; q++) {
    float4 P = pts[tid * 16 + q];
    px[q] = P.x; py[q] = P.y; pz[q] = P.z; dd[q] = 1e10f;
  }
  float lx = pts[0].x, ly = pts[0].y, lz = pts[0].z;
  for (int it = 1; it < NS; ++it) {
    float bv = -1.0f; int bq = 0;
#pragma unroll
    for (int q = 0; q < 16; q++) {
      float dx = px[q] - lx, dy = py[q] - ly, dz = pz[q] - lz;
      float d2 = dx * dx + dy * dy + dz * dz;
      float dn = fminf(dd[q], d2);
      dd[q] = dn;
      if (dn > bv) { bv = dn; bq = q; }   // ascending q keeps first on tie
    }
    const int bi = tid * 16 + bq;
    float swm = wave_umax64(bv);          // uniform, pure-VALU reduce
    unsigned long long msk = __ballot(bv == swm);
    int srcl = __ffsll(msk) - 1;          // min lane = min j (contiguous chunks)
    const int p = it & 1;
    if (lane == srcl)
      wkey[p][w] = ((unsigned long long)__float_as_uint(swm) << 32) | (unsigned)(65535 - bi);
    __syncthreads();
    unsigned long long kk = wkey[p][0];
#pragma unroll
    for (int u = 1; u < 4; u++) {
      unsigned long long o = wkey[p][u];
      if (o > kk) kk = o;
    }
    int li = 65535 - (int)(kk & 0xFFFFu);
    if (tid == 0) sel[it] = li;
    float4 L = pts[li];
    lx = L.x; ly = L.y; lz = L.z;
  }
  __syncthreads();
  for (int s = tid; s < NS; s += 256) {
    float4 P = pts[sel[s]];
    float* o = out + ((size_t)b * NS + s) * 3;
    o[0] = P.x; o[1] = P.y; o[2] = P.z;
  }
}

// ---------------------------------------------------------------- features (B,C,N)->(B,N,C)
__global__ void ft_kernel(const float* __restrict__ f, float* __restrict__ ft) {
  __shared__ float tile[32][33];
  int n0 = blockIdx.x * 32, c0 = blockIdx.y * 32, b = blockIdx.z;
  int tx = threadIdx.x, ty = threadIdx.y;  // 32x8
  for (int r = 0; r < 32; r += 8)
    tile[ty + r][tx] = f[((size_t)b * NC + (c0 + ty + r)) * NN + n0 + tx];
  __syncthreads();
  for (int r = 0; r < 32; r += 8)
    ft[((size_t)b * NN + n0 + ty + r) * NC + c0 + tx] = tile[tx][ty + r];
}

// ---------------------------------------------------------------- Wcr (256,131) -> (131,256)
__global__ void wcrt_kernel(const float* __restrict__ Wcr, float* __restrict__ wcrT) {
  int t = blockIdx.x * blockDim.x + threadIdx.x;
  if (t >= CIN * COUT) return;
  int c = t % COUT, d = t / COUT;
  wcrT[t] = Wcr[c * CIN + d];
}

// ---------------------------------------------------------------- ball query v2 (both scales)
__global__ __launch_bounds__(256) void ball_kernel(const float* __restrict__ xyz,
                                                   const float* __restrict__ nxyz,
                                                   int* __restrict__ idx0,
                                                   int* __restrict__ idx1) {
#pragma clang fp contract(off)
  __shared__ float4 pts[NN];
  const int scale = blockIdx.y;
  const int K = scale ? 64 : 32;
  const float r2 = scale ? 0.04f : 0.01f;
  int* __restrict__ idx = scale ? idx1 : idx0;
  const int lane = threadIdx.x & 63, w = threadIdx.x >> 6;
  const int c0 = blockIdx.x * 64;
  const int b = c0 >> 10;
  const float* base = xyz + (size_t)b * NN * 3;
  for (int t = threadIdx.x; t < NN; t += 256)
    pts[t] = make_float4(base[3 * t], base[3 * t + 1], base[3 * t + 2], 0.f);
  __syncthreads();
  const unsigned long long ltmask = (1ull << lane) - 1;
  for (int ci = 0; ci < 16; ci++) {
    const int center = c0 + w * 16 + ci;
    const float cx = nxyz[center * 3], cy = nxyz[center * 3 + 1], cz = nxyz[center * 3 + 2];
    int cnt = 0, first = -1;
    int* o = idx + (size_t)center * K;
    for (int st64 = 0; st64 < 64; st64++) {
      const int j = st64 * 64 + lane;
      float4 P = pts[j];
      float dx = P.x - cx, dy = P.y - cy, dz = P.z - cz;
      float d2 = dx * dx + dy * dy + dz * dz;
      const bool hit = d2 < r2;
      unsigned long long mask = __ballot(hit);
      int pos = cnt + __popcll(mask & ltmask);
      if (hit && pos < K) o[pos] = j;
      if (first < 0 && mask) first = st64 * 64 + __ffsll(mask) - 1;
      cnt += __popcll(mask);
      if (cnt >= K) break;
    }
    if (cnt < K && lane >= cnt && lane < K) o[lane] = first;
  }
}

// ---------------------------------------------------------------- P1 (both scales, 4-ch batch)
__global__ __launch_bounds__(256) void p1_kernel(
    const float* __restrict__ xyz, const float* __restrict__ nxyz,
    const int* __restrict__ idx0, const int* __restrict__ idx1,
    const float* __restrict__ W1, const float* __restrict__ b1,
    float* __restrict__ parts) {
  __shared__ float accS[MID], accQ[MID];
  const int scale = blockIdx.y;
  const int nblk = scale ? 2048 : 1024;
  if ((int)blockIdx.x >= nblk) return;
  const int K = scale ? 64 : 32, ksh = scale ? 6 : 5, G = scale ? 1 : 2;
  const int* __restrict__ idx = scale ? idx1 : idx0;
  float* __restrict__ partials = parts + (size_t)scale * PSTRIDE + (size_t)blockIdx.x * (2 * MID);
  const int tid = threadIdx.x, lane = tid & 63, wave = tid >> 6;
  if (tid < MID) { accS[tid] = 0.f; accQ[tid] = 0.f; }
  __syncthreads();
  const int sub = lane >> ksh;
  const int k = lane & (K - 1);
  const int center = blockIdx.x * (4 * G) + wave * G + sub;
  const int b = center >> 10;
  const int* ip = idx + (size_t)center * K;
  const int j = ip[k];
  const int j0 = ip[0];
  const float* xb = xyz + (size_t)b * NN * 3;
  const float gxx = xb[3 * j], gxy = xb[3 * j + 1], gxz = xb[3 * j + 2];
  const float c0x = xb[3 * j0], c0y = xb[3 * j0 + 1], c0z = xb[3 * j0 + 2];
  const float cx = nxyz[center * 3], cy = nxyz[center * 3 + 1], cz = nxyz[center * 3 + 2];
  const float rx = gxx - cx, ry = gxy - cy, rz = gxz - cz;
  const float dst = sqrtf(rx * rx + ry * ry + rz * rz + 1e-12f);
  float h[10] = {dst, c0x, c0y, c0z, gxx, gxy, gxz, rx, ry, rz};
#pragma unroll
  for (int c = 0; c < MID; c += 4) {
    float a0 = b1[c], a1 = b1[c + 1], a2 = b1[c + 2], a3 = b1[c + 3];
    const float* w0 = W1 + c * 10;
    const float* w1 = w0 + 10;
    const float* w2 = w0 + 20;
    const float* w3 = w0 + 30;
#pragma unroll
    for (int d = 0; d < 10; d++) {
      a0 += h[d] * w0[d]; a1 += h[d] * w1[d]; a2 += h[d] * w2[d]; a3 += h[d] * w3[d];
    }
    float v0 = a0, v1 = a1, v2 = a2, v3 = a3;
    wave_usum4(v0, v1, v2, v3);
    float q0 = a0 * a0, q1 = a1 * a1, q2 = a2 * a2, q3 = a3 * a3;
    wave_usum4(q0, q1, q2, q3);
    if (lane == 0) {
      atomicAdd(&accS[c], v0); atomicAdd(&accS[c + 1], v1);
      atomicAdd(&accS[c + 2], v2); atomicAdd(&accS[c + 3], v3);
      atomicAdd(&accQ[c], q0); atomicAdd(&accQ[c + 1], q1);
      atomicAdd(&accQ[c + 2], q2); atomicAdd(&accQ[c + 3], q3);
    }
  }
  __syncthreads();
  for (int t = tid; t < 2 * MID; t += 256)
    partials[t] = (t < MID ? accS[t] : accQ[t - MID]);
}

// ---------------------------------------------------------------- column reduce (both scales)
__global__ __launch_bounds__(256) void red2_kernel(const float* __restrict__ pbase,
                                                   int pstride, int nb0, int nb1,
                                                   double* __restrict__ stats, int obase) {
  __shared__ double red[256];
  const int scale = blockIdx.y;
  const int nblk = scale ? nb1 : nb0;
  const float* part = pbase + (size_t)scale * pstride;
  double* st = stats + scale * 1024;
  const int c = blockIdx.x;
  const int ncol = gridDim.x;
  double a = 0.0;
  for (int r = threadIdx.x; r < nblk; r += 256)
    a += (double)part[(size_t)r * ncol + c];
  red[threadIdx.x] = a;
  __syncthreads();
  for (int s = 128; s > 0; s >>= 1) {
    if (threadIdx.x < s) red[threadIdx.x] += red[threadIdx.x + s];
    __syncthreads();
  }
  if (threadIdx.x == 0) st[obase + c] = red[0];
}

// ---------------------------------------------------------------- P2 (both scales)
// v2f packed z matvec + all-DPP uniform reduces (no ds_bpermute in the loop).
template <bool UFT>
__global__ __launch_bounds__(256) void p2_kernel(
    const float* __restrict__ xyz, const float* __restrict__ nxyz,
    const float* __restrict__ feat, const float* __restrict__ ft,
    const int* __restrict__ idx0, const int* __restrict__ idx1,
    const float* __restrict__ W1, const float* __restrict__ b1,
    const float* __restrict__ W2, const float* __restrict__ b2,
    const float* __restrict__ g_map, const float* __restrict__ b_map,
    const double* __restrict__ stats, float* __restrict__ pm0,
    float* __restrict__ pm1, float* __restrict__ parts) {
  __shared__ float accS[CIN], accQ[CIN];
  __shared__ float sc1[MID], sh1[MID];
  const int scale = blockIdx.y;
  const int nblk = scale ? 2048 : 1024;
  if ((int)blockIdx.x >= nblk) return;
  const int K = scale ? 64 : 32, ksh = scale ? 6 : 5, G = scale ? 1 : 2;
  const int* __restrict__ idx = scale ? idx1 : idx0;
  float* __restrict__ pm = scale ? pm1 : pm0;
  const double* st = stats + scale * 1024;
  const float* g1 = g_map + scale * MID;
  const float* bt1 = b_map + scale * MID;
  float* __restrict__ partials = parts + (size_t)scale * PSTRIDE + (size_t)blockIdx.x * (2 * CIN);
  const int tid = threadIdx.x, lane = tid & 63, wave = tid >> 6;
  for (int t = tid; t < CIN; t += 256) { accS[t] = 0.f; accQ[t] = 0.f; }
  if (tid < MID) {
    const double cnt = (double)NB * NS * K;
    double mean = st[tid] / cnt;
    double var = st[64 + tid] / cnt - mean * mean;
    if (var < 0.0) var = 0.0;
    float is = (float)(1.0 / sqrt(var + 1e-5));
    float sc = g1[tid] * is;
    sc1[tid] = sc;
    sh1[tid] = bt1[tid] - (float)mean * sc;
  }
  __syncthreads();
  const int per = nblk >> 3;  // XCD swizzle
  const int lb = ((int)blockIdx.x & 7) * per + ((int)blockIdx.x >> 3);
  const int sub = lane >> ksh;
  const int k = lane & (K - 1);
  const int center = lb * (4 * G) + wave * G + sub;
  const int b = center >> 10;
  const int* ip = idx + (size_t)center * K;
  const int j = ip[k];
  const int j0 = ip[0];
  const float* xb = xyz + (size_t)b * NN * 3;
  const float gxx = xb[3 * j], gxy = xb[3 * j + 1], gxz = xb[3 * j + 2];
  const float c0x = xb[3 * j0], c0y = xb[3 * j0 + 1], c0z = xb[3 * j0 + 2];
  const float cx = nxyz[center * 3], cy = nxyz[center * 3 + 1], cz = nxyz[center * 3 + 2];
  const float rx = gxx - cx, ry = gxy - cy, rz = gxz - cz;
  const float dst = sqrtf(rx * rx + ry * ry + rz * rz + 1e-12f);
  float h[10] = {dst, c0x, c0y, c0z, gxx, gxy, gxz, rx, ry, rz};
  v2f t2[MID / 2];
#pragma unroll
  for (int c = 0; c < MID; c += 2) {
    v2f a = {b1[c], b1[c + 1]};
    const float* w0 = W1 + c * 10;
    const float* w1 = w0 + 10;
#pragma unroll
    for (int d = 0; d < 10; d++) {
      v2f wv = {w0[d], w1[d]};
      v2f hv = {h[d], h[d]};
      a = hv * wv + a;
    }
    v2f sv = {sc1[c], sc1[c + 1]};
    v2f bv = {sh1[c], sh1[c + 1]};
    v2f r = sv * a + bv;
    r[0] = fmaxf(r[0], 0.f); r[1] = fmaxf(r[1], 0.f);
    t2[c >> 1] = r;
  }
  auto chan = [&](int c, float x) {
    const float4* w4 = reinterpret_cast<const float4*>(W2 + (size_t)c * MID);
    v2f zv = {0.f, 0.f};
#pragma unroll
    for (int d4 = 0; d4 < 16; d4++) {
      float4 wq = w4[d4];
      v2f wlo = {wq.x, wq.y}, whi = {wq.z, wq.w};
      zv = t2[2 * d4] * wlo + zv;
      zv = t2[2 * d4 + 1] * whi + zv;
    }
    float z = b2[c] + zv[0] + zv[1];
    float p = z * x;
    float v = wave_usum(p);
    float q = wave_usum(p * p);
    if (lane == 0) { atomicAdd(&accS[c], v); atomicAdd(&accQ[c], q); }
    float pmax = (K == 64) ? wave_umax64(p) : wave_max32(p);
    if (k == (c & (K - 1))) pm[(size_t)center * CIN + c] = pmax;
  };
  auto chan4 = [&](int c, float x0, float x1, float x2, float x3) {
    const float4* wa = reinterpret_cast<const float4*>(W2 + (size_t)(c + 0) * MID);
    const float4* wb = reinterpret_cast<const float4*>(W2 + (size_t)(c + 1) * MID);
    const float4* wc = reinterpret_cast<const float4*>(W2 + (size_t)(c + 2) * MID);
    const float4* wd = reinterpret_cast<const float4*>(W2 + (size_t)(c + 3) * MID);
    v2f z0v = {0.f, 0.f}, z1v = {0.f, 0.f}, z2v = {0.f, 0.f}, z3v = {0.f, 0.f};
#pragma unroll
    for (int d4 = 0; d4 < 16; d4++) {
      v2f tlo = t2[2 * d4], thi = t2[2 * d4 + 1];
      float4 wq;
      wq = wa[d4]; { v2f lo = {wq.x, wq.y}, hi = {wq.z, wq.w}; z0v = tlo * lo + z0v; z0v = thi * hi + z0v; }
      wq = wb[d4]; { v2f lo = {wq.x, wq.y}, hi = {wq.z, wq.w}; z1v = tlo * lo + z1v; z1v = thi * hi + z1v; }
      wq = wc[d4]; { v2f lo = {wq.x, wq.y}, hi = {wq.z, wq.w}; z2v = tlo * lo + z2v; z2v = thi * hi + z2v; }
      wq = wd[d4]; { v2f lo = {wq.x, wq.y}, hi = {wq.z, wq.w}; z3v = tlo * lo + z3v; z3v = thi * hi + z3v; }
    }
    float p0 = (b2[c + 0] + z0v[0] + z0v[1]) * x0;
    float p1 = (b2[c + 1] + z1v[0] + z1v[1]) * x1;
    float p2 = (b2[c + 2] + z2v[0] + z2v[1]) * x2;
    float p3 = (b2[c + 3] + z3v[0] + z3v[1]) * x3;
    float v0 = p0, v1 = p1, v2 = p2, v3 = p3;
    wave_usum4(v0, v1, v2, v3);
    float q0 = p0 * p0, q1 = p1 * p1, q2 = p2 * p2, q3 = p3 * p3;
    wave_usum4(q0, q1, q2, q3);
    if (lane == 0) {
      atomicAdd(&accS[c], v0); atomicAdd(&accS[c + 1], v1);
      atomicAdd(&accS[c + 2], v2); atomicAdd(&accS[c + 3], v3);
      atomicAdd(&accQ[c], q0); atomicAdd(&accQ[c + 1], q1);
      atomicAdd(&accQ[c + 2], q2); atomicAdd(&accQ[c + 3], q3);
    }
    float m0 = p0, m1 = p1, m2 = p2, m3 = p3;
    if (K == 64) wave_umax4_64(m0, m1, m2, m3);
    else wave_max4_32(m0, m1, m2, m3);
    if (k == ((c + 0) & (K - 1))) pm[(size_t)center * CIN + c + 0] = m0;
    if (k == ((c + 1) & (K - 1))) pm[(size_t)center * CIN + c + 1] = m1;
    if (k == ((c + 2) & (K - 1))) pm[(size_t)center * CIN + c + 2] = m2;
    if (k == ((c + 3) & (K - 1))) pm[(size_t)center * CIN + c + 3] = m3;
  };
  chan(0, rx); chan(1, ry); chan(2, rz);
  const float4* ftb4 = UFT ? reinterpret_cast<const float4*>(ft + ((size_t)b * NN + j) * NC)
                           : nullptr;
  const float* fb = feat + (size_t)b * NC * NN + j;
  for (int f0 = 0; f0 < NC; f0 += 4) {
    float4 fr;
    if (UFT) {
      fr = ftb4[f0 >> 2];
    } else {
      fr.x = fb[(size_t)f0 * NN]; fr.y = fb[(size_t)(f0 + 1) * NN];
      fr.z = fb[(size_t)(f0 + 2) * NN]; fr.w = fb[(size_t)(f0 + 3) * NN];
    }
    chan4(3 + f0, fr.x, fr.y, fr.z, fr.w);
  }
  __syncthreads();
  for (int t = tid; t < 2 * CIN; t += 256)
    partials[t] = (t < CIN ? accS[t] : accQ[t - CIN]);
}

// ---------------------------------------------------------------- 131->256 linear (both scales)
__global__ __launch_bounds__(256) void s4_kernel(const float* __restrict__ pm0,
                                                 const float* __restrict__ pm1,
                                                 const float* __restrict__ wcrT,
                                                 const float* __restrict__ bcr,
                                                 const float* __restrict__ g_rs,
                                                 const float* __restrict__ b_rs,
                                                 float* __restrict__ feats,
                                                 const double* __restrict__ stats,
                                                 float* __restrict__ spart) {
  __shared__ float xms[16][132];
  __shared__ float sc2[CIN], sh2[CIN];
  const int scale = blockIdx.y;
  const int K = scale ? 64 : 32;
  const float* pm = scale ? pm1 : pm0;
  const double* st = stats + scale * 1024;
  const float* g2 = g_rs + scale * CIN;
  const float* bt2 = b_rs + scale * CIN;
  const int choff = scale << 8;
  float* sp = spart + (size_t)scale * SSTRIDE + (size_t)blockIdx.x * 512;
  const int tid = threadIdx.x;
  if (tid < CIN) {
    const double cnt = (double)NB * NS * K;
    double mean = st[128 + tid] / cnt;
    double var = st[259 + tid] / cnt - mean * mean;
    if (var < 0.0) var = 0.0;
    float is = (float)(1.0 / sqrt(var + 1e-5));
    float sc = g2[tid] * is;
    sc2[tid] = sc;
    sh2[tid] = bt2[tid] - (float)mean * sc;
  }
  float bc = bcr[tid];
  float s1 = 0.f, s2 = 0.f;
  __syncthreads();
  for (int r0 = blockIdx.x * 16; r0 < NB * NS; r0 += gridDim.x * 16) {
    for (int t = tid; t < 16 * CIN; t += 256) {
      int rr = t / CIN, cc = t % CIN;
      xms[rr][cc] = fmaxf(sc2[cc] * pm[(size_t)(r0 + rr) * CIN + cc] + sh2[cc], 0.0f);
    }
    __syncthreads();
    float acc[16];
#pragma unroll
    for (int u = 0; u < 16; u++) acc[u] = bc;
    for (int d4 = 0; d4 < 32; d4++) {
      float w0 = wcrT[(4 * d4 + 0) * COUT + tid];
      float w1 = wcrT[(4 * d4 + 1) * COUT + tid];
      float w2 = wcrT[(4 * d4 + 2) * COUT + tid];
      float w3 = wcrT[(4 * d4 + 3) * COUT + tid];
#pragma unroll
      for (int u = 0; u < 16; u++) {
        float4 xv = *reinterpret_cast<const float4*>(&xms[u][4 * d4]);
        acc[u] += xv.x * w0 + xv.y * w1 + xv.z * w2 + xv.w * w3;
      }
    }
#pragma unroll
    for (int d = 128; d < CIN; d++) {
      float w = wcrT[d * COUT + tid];
#pragma unroll
      for (int u = 0; u < 16; u++) acc[u] += xms[u][d] * w;
    }
#pragma unroll
    for (int u = 0; u < 16; u++) {
      int r = r0 + u;
      int b = r >> 10, s = r & (NS - 1);
      feats[((size_t)b * 512 + choff + tid) * NS + s] = acc[u];
      s1 += acc[u];
      s2 += acc[u] * acc[u];
    }
    __syncthreads();
  }
  sp[tid] = s1;
  sp[256 + tid] = s2;
}

// ---------------------------------------------------------------- BN3 + relu in place
__global__ void s5_kernel(float* __restrict__ feats, const double* __restrict__ stats,
                          const float* __restrict__ g_cr, const float* __restrict__ b_cr) {
  const int scale = blockIdx.y;
  const double* st = stats + scale * 1024;
  int t = blockIdx.x * blockDim.x + threadIdx.x;
  int s = t & (NS - 1);
  int c = (t >> 10) & (COUT - 1);
  int b = t >> 18;
  double mean = st[512 + c] / (double)(NB * NS);
  double var = st[768 + c] / (double)(NB * NS) - mean * mean;
  if (var < 0.0) var = 0.0;
  float is = (float)(1.0 / sqrt(var + 1e-5));
  float sc = g_cr[scale * 256 + c] * is;
  float sh = b_cr[scale * 256 + c] - (float)mean * sc;
  size_t o = ((size_t)b * 512 + scale * 256 + c) * NS + s;
  feats[o] = fmaxf(sc * feats[o] + sh, 0.0f);
}

// ================================================================ host
extern "C" void kernel_launch(void* const* d_in, const int* in_sizes, int n_in,
                              void* d_out, int out_size, void* d_ws, size_t ws_size,
                              hipStream_t stream) {
  const float* xyz  = (const float*)d_in[0];
  const float* feat = (const float*)d_in[1];
  const float* W1   = (const float*)d_in[2];
  const float* b1   = (const float*)d_in[3];
  const float* W2   = (const float*)d_in[4];
  const float* b2   = (const float*)d_in[5];
  const float* Wcr  = (const float*)d_in[6];
  const float* bcr  = (const float*)d_in[7];
  const float* g_map = (const float*)d_in[8];
  const float* b_map = (const float*)d_in[9];
  const float* g_rs  = (const float*)d_in[10];
  const float* b_rs  = (const float*)d_in[11];
  const float* g_cr  = (const float*)d_in[12];
  const float* b_cr  = (const float*)d_in[13];

  char* wsb = (char*)d_ws;
  size_t off = 0;
  auto take = [&](size_t bytes) -> void* {
    void* p = wsb + off;
    off = (off + bytes + 255) & ~(size_t)255;
    return p;
  };
  int*    idxb0 = (int*)take((size_t)NB * NS * 32 * sizeof(int));
  int*    idxb1 = (int*)take((size_t)NB * NS * 64 * sizeof(int));
  float*  pm0   = (float*)take((size_t)NB * NS * CIN * sizeof(float));
  float*  pm1   = (float*)take((size_t)NB * NS * CIN * sizeof(float));
  float*  wcrT  = (float*)take((size_t)CIN * COUT * sizeof(float));
  double* stats = (double*)take(2048 * sizeof(double));
  float*  parts = (float*)take((size_t)2 * PSTRIDE * sizeof(float));
  float*  spart = (float*)take((size_t)2 * SSTRIDE * sizeof(float));
  float*  ft    = nullptr;
  if (off + (size_t)NB * NN * NC * sizeof(float) + 256 <= ws_size)
    ft = (float*)take((size_t)NB * NN * NC * sizeof(float));

  float* out = (float*)d_out;
  float* feats = out + NB * NS * 3;

  fps_kernel<<<NB, 256, 0, stream>>>(xyz, out);
  if (ft) ft_kernel<<<dim3(NN / 32, NC / 32, NB), dim3(32, 8), 0, stream>>>(feat, ft);
  wcrt_kernel<<<(CIN * COUT + 255) / 256, 256, 0, stream>>>(Wcr, wcrT);
  ball_kernel<<<dim3(128, 2), 256, 0, stream>>>(xyz, out, idxb0, idxb1);
  p1_kernel<<<dim3(2048, 2), 256, 0, stream>>>(xyz, out, idxb0, idxb1, W1, b1, parts);
  red2_kernel<<<dim3(2 * MID, 2), 256, 0, stream>>>(parts, PSTRIDE, 1024, 2048, stats, 0);
  if (ft)
    p2_kernel<true><<<dim3(2048, 2), 256, 0, stream>>>(xyz, out, feat, ft, idxb0, idxb1,
                                                       W1, b1, W2, b2, g_map, b_map,
                                                       stats, pm0, pm1, parts);
  else
    p2_kernel<false><<<dim3(2048, 2), 256, 0, stream>>>(xyz, out, feat, ft, idxb0, idxb1,
                                                        W1, b1, W2, b2, g_map, b_map,
                                                        stats, pm0, pm1, parts);
  red2_kernel<<<dim3(2 * CIN, 2), 256, 0, stream>>>(parts, PSTRIDE, 1024, 2048, stats, 128);
  s4_kernel<<<dim3(256, 2), 256, 0, stream>>>(pm0, pm1, wcrT, bcr, g_rs, b_rs, feats,
                                              stats, spart);
  red2_kernel<<<dim3(512, 2), 256, 0, stream>>>(spart, SSTRIDE, 256, 256, stats, 512);
  s5_kernel<<<dim3((NB * COUT * NS) / 256, 2), 256, 0, stream>>>(feats, stats, g_cr, b_cr);
  (void)in_sizes; (void)n_in; (void)out_size;
}